// Round 2
// baseline (179.067 us; speedup 1.0000x reference)
//
#include <hip/hip_runtime.h>
#include <hip/hip_bf16.h>

// SimCLR NT-Xent loss on MI355X.
// loss = -(1/2B) sum_t [ 10*G[t,j0(t)] - (10 + log sum_{j!=t} exp(10*G[t,j]-10)) ]
// where G = M M^T, M = l2norm rows of [z_i; z_j], j0 = (t%B==0) ? 1 : 0.
// Round 2: symmetric upper-triangle tiles (2080 blocks), fused finalize via
// completion counter, memset folded into normalize. 2 graph nodes total.

#define BB 4096      // batch B
#define DD 512       // feature dim
#define NN 8192      // 2B rows of G
#define TILE 128     // block tile (rows x cols)
#define KC 64        // K staged per LDS chunk
#define NBLK 2080    // 64*65/2 upper-triangle block tiles

typedef __attribute__((ext_vector_type(8))) short short8;
typedef __attribute__((ext_vector_type(4))) float f32x4;

// ---------------- kernel 1: L2-normalize rows, cast to bf16; zero ws -------
__global__ __launch_bounds__(256)
void normalize_kernel(const float* __restrict__ zi, const float* __restrict__ zj,
                      __hip_bfloat16* __restrict__ M, float* __restrict__ rowsum,
                      unsigned* __restrict__ counter) {
    const int row = blockIdx.x;                 // 0..8191
    const int tid = threadIdx.x;                // 0..255, 2 floats each
    if (tid == 0) rowsum[row] = 0.f;
    if (row == 0 && tid == 1) *counter = 0u;
    const float* src = (row < BB) ? (zi + (size_t)row * DD)
                                  : (zj + (size_t)(row - BB) * DD);
    float2 v = ((const float2*)src)[tid];
    float ss = v.x * v.x + v.y * v.y;
    #pragma unroll
    for (int off = 32; off; off >>= 1) ss += __shfl_down(ss, off);
    __shared__ float red[4];
    if ((tid & 63) == 0) red[tid >> 6] = ss;
    __syncthreads();
    float tot = red[0] + red[1] + red[2] + red[3];
    float inv = rsqrtf(tot);
    __hip_bfloat162 o;
    o.x = __float2bfloat16(v.x * inv);
    o.y = __float2bfloat16(v.y * inv);
    ((__hip_bfloat162*)(M + (size_t)row * DD))[tid] = o;
}

// ---------------- kernel 2: Gram tile + exp sums + fused finalize ----------
// 2080 blocks, each one upper-triangle 128x128 tile (by >= bx).
// Wave w: rows wr=(w>>1)*64, cols wc=(w&1)*64 within the tile.
__global__ __launch_bounds__(256, 4)
void gram_lse_kernel(const __hip_bfloat16* __restrict__ Mb,
                     float* __restrict__ rowsum, float* __restrict__ targets,
                     unsigned* __restrict__ counter, float* __restrict__ out) {
    __shared__ __align__(16) short As[TILE * KC];   // 16 KB, XOR-swizzled granules
    __shared__ __align__(16) short Bs[TILE * KC];   // 16 KB

    // triangular decode: p -> (bx, by) with by >= bx
    const int p = blockIdx.x;
    int by = (int)((sqrtf(8.0f * (float)p + 1.0f) - 1.0f) * 0.5f);
    while ((by + 1) * (by + 2) / 2 <= p) ++by;
    while (by * (by + 1) / 2 > p) --by;
    const int bx = p - by * (by + 1) / 2;

    const int rowBase = bx * TILE;
    const int colBase = by * TILE;
    const bool diag = (bx == by);
    const int tid  = threadIdx.x;
    const int wave = tid >> 6;
    const int lane = tid & 63;
    const int wr = (wave >> 1) * 64;
    const int wc = (wave & 1) * 64;
    const int l15 = lane & 15;
    const int l4  = lane >> 4;          // quad 0..3

    const short* Mg = (const short*)Mb;
    const short8* BsR = diag ? (const short8*)As : (const short8*)Bs;

    f32x4 acc[4][4] = {};

    for (int k0 = 0; k0 < DD; k0 += KC) {
        __syncthreads();   // previous-iteration LDS reads done
        // stage 128 rows x 64 k: 1024 16B-granules each; 4 per thread.
        #pragma unroll
        for (int i = 0; i < 4; ++i) {
            int pos = tid + 256 * i;    // 0..1023
            int row = pos >> 3;         // 8 granules per row
            int g   = pos & 7;
            short8 av = *(const short8*)(Mg + (size_t)(rowBase + row) * DD + k0 + g * 8);
            ((short8*)As)[row * 8 + (g ^ (row & 7))] = av;
            if (!diag) {
                short8 bv = *(const short8*)(Mg + (size_t)(colBase + row) * DD + k0 + g * 8);
                ((short8*)Bs)[row * 8 + (g ^ (row & 7))] = bv;
            }
        }
        __syncthreads();
        #pragma unroll
        for (int ks = 0; ks < KC / 32; ++ks) {
            const int gk = ks * 4 + l4;         // granule index within row
            short8 a[4], b[4];
            #pragma unroll
            for (int mi = 0; mi < 4; ++mi) {
                int row = wr + mi * 16 + l15;
                a[mi] = ((const short8*)As)[row * 8 + (gk ^ (row & 7))];
            }
            #pragma unroll
            for (int ni = 0; ni < 4; ++ni) {
                int row = wc + ni * 16 + l15;
                b[ni] = BsR[row * 8 + (gk ^ (row & 7))];
            }
            #pragma unroll
            for (int mi = 0; mi < 4; ++mi)
                #pragma unroll
                for (int ni = 0; ni < 4; ++ni)
                    acc[mi][ni] = __builtin_amdgcn_mfma_f32_16x16x32_bf16(
                        a[mi], b[ni], acc[mi][ni], 0, 0, 0);
        }
    }

    // ---- epilogue ----
    // C/D layout: col = lane&15, row = (lane>>4)*4 + reg   [verified m89/m91]
    float cs[4] = {0.f, 0.f, 0.f, 0.f};   // column partials (off-diag tiles)
    #pragma unroll
    for (int mi = 0; mi < 4; ++mi) {
        float rs[4] = {0.f, 0.f, 0.f, 0.f};
        #pragma unroll
        for (int ni = 0; ni < 4; ++ni) {
            const int gcol = colBase + wc + ni * 16 + l15;
            #pragma unroll
            for (int r = 0; r < 4; ++r) {
                const int grow = rowBase + wr + mi * 16 + l4 * 4 + r;
                float logit = 10.f * acc[mi][ni][r];
                float e = __expf(logit - 10.f);
                if (grow == gcol) e = 0.f;     // exclude diagonal exactly
                rs[r] += e;
                cs[ni] += e;
                // targets: rows 0/1 of G give 10*G[t, j0] transposed.
                if (rowBase == 0 && grow < 2) {
                    const int j0 = ((gcol & (BB - 1)) == 0) ? 1 : 0;
                    if (grow == j0)
                        __hip_atomic_store(&targets[gcol], logit,
                                           __ATOMIC_RELAXED, __HIP_MEMORY_SCOPE_AGENT);
                }
            }
        }
        #pragma unroll
        for (int m = 1; m <= 8; m <<= 1)
            #pragma unroll
            for (int r = 0; r < 4; ++r)
                rs[r] += __shfl_xor(rs[r], m);
        if (l15 == 0) {
            #pragma unroll
            for (int r = 0; r < 4; ++r)
                atomicAdd(&rowsum[rowBase + wr + mi * 16 + l4 * 4 + r], rs[r]);
        }
    }
    if (!diag) {
        #pragma unroll
        for (int ni = 0; ni < 4; ++ni) {
            cs[ni] += __shfl_xor(cs[ni], 16);
            cs[ni] += __shfl_xor(cs[ni], 32);
        }
        if (l4 == 0) {
            #pragma unroll
            for (int ni = 0; ni < 4; ++ni)
                atomicAdd(&rowsum[colBase + wc + ni * 16 + l15], cs[ni]);
        }
    }

    // ---- completion counter + fused finalize (last block) ----
    __syncthreads();   // drain this block's outstanding stores/atomics (vmcnt0 before barrier)
    __shared__ int lastFlag;
    if (tid == 0) {
        unsigned old = __hip_atomic_fetch_add(counter, 1u,
                                              __ATOMIC_ACQ_REL, __HIP_MEMORY_SCOPE_AGENT);
        lastFlag = (old == NBLK - 1);
    }
    __syncthreads();
    if (lastFlag) {
        float s = 0.f;
        for (int t = tid; t < NN; t += 256) {
            float rsv = __hip_atomic_load(&rowsum[t],  __ATOMIC_RELAXED, __HIP_MEMORY_SCOPE_AGENT);
            float tv  = __hip_atomic_load(&targets[t], __ATOMIC_RELAXED, __HIP_MEMORY_SCOPE_AGENT);
            s += tv - 10.f - __logf(rsv);
        }
        #pragma unroll
        for (int off = 32; off; off >>= 1) s += __shfl_down(s, off);
        __shared__ float red[4];
        if ((tid & 63) == 0) red[tid >> 6] = s;
        __syncthreads();
        if (tid == 0) out[0] = -(red[0] + red[1] + red[2] + red[3]) / (float)NN;
    }
}

extern "C" void kernel_launch(void* const* d_in, const int* in_sizes, int n_in,
                              void* d_out, int out_size, void* d_ws, size_t ws_size,
                              hipStream_t stream) {
    const float* zi = (const float*)d_in[0];
    const float* zj = (const float*)d_in[1];

    __hip_bfloat16* M = (__hip_bfloat16*)d_ws;                       // 8 MB
    float* rowsum  = (float*)((char*)d_ws + (size_t)NN * DD * 2);    // 32 KB
    float* targets = rowsum + NN;                                    // 32 KB
    unsigned* counter = (unsigned*)(targets + NN);                   // 4 B
    float* out = (float*)d_out;

    normalize_kernel<<<NN, 256, 0, stream>>>(zi, zj, M, rowsum, counter);
    gram_lse_kernel<<<NBLK, 256, 0, stream>>>(M, rowsum, targets, counter, out);
}

// Round 3
// 139.031 us; speedup vs baseline: 1.2880x; 1.2880x over previous
//
#include <hip/hip_runtime.h>
#include <hip/hip_bf16.h>

// SimCLR NT-Xent loss on MI355X.
// loss = -(1/2B) sum_t [ 10*G[t,j0(t)] - (10 + log sum_{j!=t} exp(10*G[t,j]-10)) ]
// where G = M M^T, M = l2norm rows of [z_i; z_j], j0 = (t%B==0) ? 1 : 0.
// Round 3: symmetric upper-triangle tiles (2080 blocks) with RELAXED atomics
// only (round 2's ACQ_REL completion counter caused per-block L2 wb/inv ->
// FETCH/WRITE doubling). Separate tiny finalize kernel (3 nodes).

#define BB 4096      // batch B
#define DD 512       // feature dim
#define NN 8192      // 2B rows of G
#define TILE 128     // block tile (rows x cols)
#define KC 64        // K staged per LDS chunk
#define NBLK 2080    // 64*65/2 upper-triangle block tiles

typedef __attribute__((ext_vector_type(8))) short short8;
typedef __attribute__((ext_vector_type(4))) float f32x4;

// ---------------- kernel 1: L2-normalize rows, cast to bf16; zero rowsum ---
__global__ __launch_bounds__(256)
void normalize_kernel(const float* __restrict__ zi, const float* __restrict__ zj,
                      __hip_bfloat16* __restrict__ M, float* __restrict__ rowsum) {
    const int row = blockIdx.x;                 // 0..8191
    const int tid = threadIdx.x;                // 0..255, 2 floats each
    if (tid == 0) rowsum[row] = 0.f;
    const float* src = (row < BB) ? (zi + (size_t)row * DD)
                                  : (zj + (size_t)(row - BB) * DD);
    float2 v = ((const float2*)src)[tid];
    float ss = v.x * v.x + v.y * v.y;
    #pragma unroll
    for (int off = 32; off; off >>= 1) ss += __shfl_down(ss, off);
    __shared__ float red[4];
    if ((tid & 63) == 0) red[tid >> 6] = ss;
    __syncthreads();
    float tot = red[0] + red[1] + red[2] + red[3];
    float inv = rsqrtf(tot);
    __hip_bfloat162 o;
    o.x = __float2bfloat16(v.x * inv);
    o.y = __float2bfloat16(v.y * inv);
    ((__hip_bfloat162*)(M + (size_t)row * DD))[tid] = o;
}

// ---------------- kernel 2: Gram tile + exp row/col sums -------------------
// 2080 blocks, each one upper-triangle 128x128 tile (by >= bx).
// Wave w: rows wr=(w>>1)*64, cols wc=(w&1)*64 within the tile.
__global__ __launch_bounds__(256, 2)
void gram_lse_kernel(const __hip_bfloat16* __restrict__ Mb,
                     float* __restrict__ rowsum, float* __restrict__ targets) {
    __shared__ __align__(16) short As[TILE * KC];   // 16 KB, XOR-swizzled granules
    __shared__ __align__(16) short Bs[TILE * KC];   // 16 KB

    // triangular decode: p -> (bx, by) with by >= bx
    const int p = blockIdx.x;
    int by = (int)((sqrtf(8.0f * (float)p + 1.0f) - 1.0f) * 0.5f);
    while ((by + 1) * (by + 2) / 2 <= p) ++by;
    while (by * (by + 1) / 2 > p) --by;
    const int bx = p - by * (by + 1) / 2;

    const int rowBase = bx * TILE;
    const int colBase = by * TILE;
    const bool diag = (bx == by);
    const int tid  = threadIdx.x;
    const int wave = tid >> 6;
    const int lane = tid & 63;
    const int wr = (wave >> 1) * 64;
    const int wc = (wave & 1) * 64;
    const int l15 = lane & 15;
    const int l4  = lane >> 4;          // quad 0..3

    const short* Mg = (const short*)Mb;
    const short8* BsR = diag ? (const short8*)As : (const short8*)Bs;

    f32x4 acc[4][4] = {};

    for (int k0 = 0; k0 < DD; k0 += KC) {
        __syncthreads();   // previous-iteration LDS reads done
        // stage 128 rows x 64 k: 1024 16B-granules each; 4 per thread.
        #pragma unroll
        for (int i = 0; i < 4; ++i) {
            int pos = tid + 256 * i;    // 0..1023
            int row = pos >> 3;         // 8 granules per row
            int g   = pos & 7;
            short8 av = *(const short8*)(Mg + (size_t)(rowBase + row) * DD + k0 + g * 8);
            ((short8*)As)[row * 8 + (g ^ (row & 7))] = av;
            if (!diag) {
                short8 bv = *(const short8*)(Mg + (size_t)(colBase + row) * DD + k0 + g * 8);
                ((short8*)Bs)[row * 8 + (g ^ (row & 7))] = bv;
            }
        }
        __syncthreads();
        #pragma unroll
        for (int ks = 0; ks < KC / 32; ++ks) {
            const int gk = ks * 4 + l4;         // granule index within row
            short8 a[4], b[4];
            #pragma unroll
            for (int mi = 0; mi < 4; ++mi) {
                int row = wr + mi * 16 + l15;
                a[mi] = ((const short8*)As)[row * 8 + (gk ^ (row & 7))];
            }
            #pragma unroll
            for (int ni = 0; ni < 4; ++ni) {
                int row = wc + ni * 16 + l15;
                b[ni] = BsR[row * 8 + (gk ^ (row & 7))];
            }
            #pragma unroll
            for (int mi = 0; mi < 4; ++mi)
                #pragma unroll
                for (int ni = 0; ni < 4; ++ni)
                    acc[mi][ni] = __builtin_amdgcn_mfma_f32_16x16x32_bf16(
                        a[mi], b[ni], acc[mi][ni], 0, 0, 0);
        }
    }

    // ---- epilogue ----
    // C/D layout: col = lane&15, row = (lane>>4)*4 + reg   [verified m89/m91]
    float cs[4] = {0.f, 0.f, 0.f, 0.f};   // column partials (off-diag tiles)
    #pragma unroll
    for (int mi = 0; mi < 4; ++mi) {
        float rs[4] = {0.f, 0.f, 0.f, 0.f};
        #pragma unroll
        for (int ni = 0; ni < 4; ++ni) {
            const int gcol = colBase + wc + ni * 16 + l15;
            #pragma unroll
            for (int r = 0; r < 4; ++r) {
                const int grow = rowBase + wr + mi * 16 + l4 * 4 + r;
                float logit = 10.f * acc[mi][ni][r];
                float e = __expf(logit - 10.f);
                if (grow == gcol) e = 0.f;     // exclude diagonal exactly
                rs[r] += e;
                cs[ni] += e;
                // targets: rows 0/1 of G give 10*G[t, j0] transposed.
                // Only bx==0 blocks write; disjoint col ranges -> plain store.
                if (rowBase == 0 && grow < 2) {
                    const int j0 = ((gcol & (BB - 1)) == 0) ? 1 : 0;
                    if (grow == j0) targets[gcol] = logit;
                }
            }
        }
        #pragma unroll
        for (int m = 1; m <= 8; m <<= 1)
            #pragma unroll
            for (int r = 0; r < 4; ++r)
                rs[r] += __shfl_xor(rs[r], m);
        if (l15 == 0) {
            #pragma unroll
            for (int r = 0; r < 4; ++r)
                atomicAdd(&rowsum[rowBase + wr + mi * 16 + l4 * 4 + r], rs[r]);
        }
    }
    if (!diag) {
        #pragma unroll
        for (int ni = 0; ni < 4; ++ni) {
            cs[ni] += __shfl_xor(cs[ni], 16);
            cs[ni] += __shfl_xor(cs[ni], 32);
        }
        if (l4 == 0) {
            #pragma unroll
            for (int ni = 0; ni < 4; ++ni)
                atomicAdd(&rowsum[colBase + wc + ni * 16 + l15], cs[ni]);
        }
    }
}

// ---------------- kernel 3: final scalar reduction -------------------------
__global__ __launch_bounds__(256)
void finalize_kernel(const float* __restrict__ rowsum,
                     const float* __restrict__ targets, float* __restrict__ out) {
    const int tid = threadIdx.x;
    float s = 0.f;
    for (int t = tid; t < NN; t += 256)
        s += targets[t] - 10.f - __logf(rowsum[t]);
    #pragma unroll
    for (int off = 32; off; off >>= 1) s += __shfl_down(s, off);
    __shared__ float red[4];
    if ((tid & 63) == 0) red[tid >> 6] = s;
    __syncthreads();
    if (tid == 0) out[0] = -(red[0] + red[1] + red[2] + red[3]) / (float)NN;
}

extern "C" void kernel_launch(void* const* d_in, const int* in_sizes, int n_in,
                              void* d_out, int out_size, void* d_ws, size_t ws_size,
                              hipStream_t stream) {
    const float* zi = (const float*)d_in[0];
    const float* zj = (const float*)d_in[1];

    __hip_bfloat16* M = (__hip_bfloat16*)d_ws;                       // 8 MB
    float* rowsum  = (float*)((char*)d_ws + (size_t)NN * DD * 2);    // 32 KB
    float* targets = rowsum + NN;                                    // 32 KB
    float* out = (float*)d_out;

    normalize_kernel<<<NN, 256, 0, stream>>>(zi, zj, M, rowsum);
    gram_lse_kernel<<<NBLK, 256, 0, stream>>>(M, rowsum, targets);
    finalize_kernel<<<1, 256, 0, stream>>>(rowsum, targets, out);
}

// Round 4
// 123.461 us; speedup vs baseline: 1.4504x; 1.1261x over previous
//
#include <hip/hip_runtime.h>
#include <hip/hip_bf16.h>

// SimCLR NT-Xent loss on MI355X.
// loss = -(1/2B) sum_t [ 10*G[t,j0(t)] - (10 + log sum_{j!=t} exp(10*G[t,j]-10)) ]
// where G = M M^T, M = l2norm rows of [z_i; z_j], j0 = (t%B==0) ? 1 : 0.
// Round 4: staging via global_load_lds (16B, direct-to-LDS, swizzle inverted
// on the gather side), launch_bounds(256,4) for ~4 blocks/CU, wave-per-row
// normalize. Relaxed atomics only (round-2 lesson: no device-scope fences).

#define BB 4096      // batch B
#define DD 512       // feature dim
#define NN 8192      // 2B rows of G
#define TILE 128     // block tile (rows x cols)
#define KC 64        // K staged per LDS chunk
#define NBLK 2080    // 64*65/2 upper-triangle block tiles

typedef __attribute__((ext_vector_type(8))) short short8;
typedef __attribute__((ext_vector_type(4))) float f32x4;

#define AS1 __attribute__((address_space(1)))
#define AS3 __attribute__((address_space(3)))
static __device__ __forceinline__ void gload_lds16(const void* g, void* l) {
    __builtin_amdgcn_global_load_lds((const AS1 void*)g, (AS3 void*)l, 16, 0, 0);
}

// ---------------- kernel 1: L2-normalize rows, cast to bf16; zero rowsum ---
// One wave per row: 64 lanes x 8 f32, shuffle reduce, no LDS/barrier.
__global__ __launch_bounds__(256)
void normalize_kernel(const float* __restrict__ zi, const float* __restrict__ zj,
                      __hip_bfloat16* __restrict__ M, float* __restrict__ rowsum) {
    const int wave = threadIdx.x >> 6;
    const int lane = threadIdx.x & 63;
    const int row  = blockIdx.x * 4 + wave;      // 2048 blocks * 4 rows
    if (threadIdx.x < 4) rowsum[blockIdx.x * 4 + threadIdx.x] = 0.f;
    const float* src = (row < BB) ? (zi + (size_t)row * DD)
                                  : (zj + (size_t)(row - BB) * DD);
    float4 v0 = ((const float4*)src)[lane * 2 + 0];
    float4 v1 = ((const float4*)src)[lane * 2 + 1];
    float ss = v0.x*v0.x + v0.y*v0.y + v0.z*v0.z + v0.w*v0.w
             + v1.x*v1.x + v1.y*v1.y + v1.z*v1.z + v1.w*v1.w;
    #pragma unroll
    for (int off = 1; off <= 32; off <<= 1) ss += __shfl_xor(ss, off);
    const float inv = rsqrtf(ss);
    short8 o;
    o[0] = (short)__bfloat16_as_ushort(__float2bfloat16(v0.x * inv));
    o[1] = (short)__bfloat16_as_ushort(__float2bfloat16(v0.y * inv));
    o[2] = (short)__bfloat16_as_ushort(__float2bfloat16(v0.z * inv));
    o[3] = (short)__bfloat16_as_ushort(__float2bfloat16(v0.w * inv));
    o[4] = (short)__bfloat16_as_ushort(__float2bfloat16(v1.x * inv));
    o[5] = (short)__bfloat16_as_ushort(__float2bfloat16(v1.y * inv));
    o[6] = (short)__bfloat16_as_ushort(__float2bfloat16(v1.z * inv));
    o[7] = (short)__bfloat16_as_ushort(__float2bfloat16(v1.w * inv));
    ((short8*)(M + (size_t)row * DD))[lane] = o;
}

// ---------------- kernel 2: Gram tile + exp row/col sums -------------------
// 2080 blocks, each one upper-triangle 128x128 tile (by >= bx).
// Wave w: rows wr=(w>>1)*64, cols wc=(w&1)*64 within the tile.
// LDS layout: granule q holds (row=q>>3, g=(q&7)^((q>>3)&7)) -- XOR swizzle,
// conflict-free b128 reads; gather side inverts the swizzle so the
// global_load_lds lane-linear dest constraint is satisfied.
__global__ __launch_bounds__(256, 4)
void gram_lse_kernel(const __hip_bfloat16* __restrict__ Mb,
                     float* __restrict__ rowsum, float* __restrict__ targets) {
    __shared__ __align__(16) short As[TILE * KC];   // 16 KB
    __shared__ __align__(16) short Bs[TILE * KC];   // 16 KB

    // triangular decode: p -> (bx, by) with by >= bx
    const int p = blockIdx.x;
    int by = (int)((sqrtf(8.0f * (float)p + 1.0f) - 1.0f) * 0.5f);
    while ((by + 1) * (by + 2) / 2 <= p) ++by;
    while (by * (by + 1) / 2 > p) --by;
    const int bx = p - by * (by + 1) / 2;

    const int rowBase = bx * TILE;
    const int colBase = by * TILE;
    const bool diag = (bx == by);
    const int tid  = threadIdx.x;
    const int wave = tid >> 6;
    const int lane = tid & 63;
    const int wr = (wave >> 1) * 64;
    const int wc = (wave & 1) * 64;
    const int l15 = lane & 15;
    const int l4  = lane >> 4;          // quad 0..3

    const short* Mg = (const short*)Mb;
    const short8* BsR = diag ? (const short8*)As : (const short8*)Bs;

    // staging gather pattern (constant per thread across issues & k0):
    const int sg  = (tid & 7) ^ ((tid >> 3) & 7);   // source granule within row
    const int sr0 = tid >> 3;                        // source row base (+32/issue)
    const short* gA0 = Mg + (size_t)(rowBase + sr0) * DD + sg * 8;
    const short* gB0 = Mg + (size_t)(colBase + sr0) * DD + sg * 8;
    short* lA0 = As + tid * 8;                       // granule q = tid (+256/issue)
    short* lB0 = Bs + tid * 8;

    f32x4 acc[4][4] = {};

    for (int k0 = 0; k0 < DD; k0 += KC) {
        __syncthreads();   // previous-iteration LDS reads done
        #pragma unroll
        for (int i = 0; i < 4; ++i)
            gload_lds16(gA0 + k0 + (size_t)i * 32 * DD, lA0 + i * 2048);
        if (!diag) {
            #pragma unroll
            for (int i = 0; i < 4; ++i)
                gload_lds16(gB0 + k0 + (size_t)i * 32 * DD, lB0 + i * 2048);
        }
        __syncthreads();   // drains vmcnt(0): staging complete
        #pragma unroll
        for (int ks = 0; ks < KC / 32; ++ks) {
            const int gk = ks * 4 + l4;         // granule index within row
            short8 a[4], b[4];
            #pragma unroll
            for (int mi = 0; mi < 4; ++mi) {
                int row = wr + mi * 16 + l15;
                a[mi] = ((const short8*)As)[row * 8 + (gk ^ (row & 7))];
            }
            #pragma unroll
            for (int ni = 0; ni < 4; ++ni) {
                int row = wc + ni * 16 + l15;
                b[ni] = BsR[row * 8 + (gk ^ (row & 7))];
            }
            #pragma unroll
            for (int mi = 0; mi < 4; ++mi)
                #pragma unroll
                for (int ni = 0; ni < 4; ++ni)
                    acc[mi][ni] = __builtin_amdgcn_mfma_f32_16x16x32_bf16(
                        a[mi], b[ni], acc[mi][ni], 0, 0, 0);
        }
    }

    // ---- epilogue ----
    // C/D layout: col = lane&15, row = (lane>>4)*4 + reg   [verified m89/m91]
    float cs[4] = {0.f, 0.f, 0.f, 0.f};   // column partials (off-diag tiles)
    #pragma unroll
    for (int mi = 0; mi < 4; ++mi) {
        float rs[4] = {0.f, 0.f, 0.f, 0.f};
        #pragma unroll
        for (int ni = 0; ni < 4; ++ni) {
            const int gcol = colBase + wc + ni * 16 + l15;
            #pragma unroll
            for (int r = 0; r < 4; ++r) {
                const int grow = rowBase + wr + mi * 16 + l4 * 4 + r;
                float logit = 10.f * acc[mi][ni][r];
                float e = __expf(logit - 10.f);
                if (grow == gcol) e = 0.f;     // exclude diagonal exactly
                rs[r] += e;
                cs[ni] += e;
                // targets: rows 0/1 of G give 10*G[t, j0] transposed.
                // Only bx==0 blocks write; disjoint col ranges -> plain store.
                if (rowBase == 0 && grow < 2) {
                    const int j0 = ((gcol & (BB - 1)) == 0) ? 1 : 0;
                    if (grow == j0) targets[gcol] = logit;
                }
            }
        }
        #pragma unroll
        for (int m = 1; m <= 8; m <<= 1)
            #pragma unroll
            for (int r = 0; r < 4; ++r)
                rs[r] += __shfl_xor(rs[r], m);
        if (l15 == 0) {
            #pragma unroll
            for (int r = 0; r < 4; ++r)
                atomicAdd(&rowsum[rowBase + wr + mi * 16 + l4 * 4 + r], rs[r]);
        }
    }
    if (!diag) {
        #pragma unroll
        for (int ni = 0; ni < 4; ++ni) {
            cs[ni] += __shfl_xor(cs[ni], 16);
            cs[ni] += __shfl_xor(cs[ni], 32);
        }
        if (l4 == 0) {
            #pragma unroll
            for (int ni = 0; ni < 4; ++ni)
                atomicAdd(&rowsum[colBase + wc + ni * 16 + l15], cs[ni]);
        }
    }
}

// ---------------- kernel 3: final scalar reduction -------------------------
__global__ __launch_bounds__(256)
void finalize_kernel(const float* __restrict__ rowsum,
                     const float* __restrict__ targets, float* __restrict__ out) {
    const int tid = threadIdx.x;
    float s = 0.f;
    for (int t = tid; t < NN; t += 256)
        s += targets[t] - 10.f - __logf(rowsum[t]);
    #pragma unroll
    for (int off = 32; off; off >>= 1) s += __shfl_down(s, off);
    __shared__ float red[4];
    if ((tid & 63) == 0) red[tid >> 6] = s;
    __syncthreads();
    if (tid == 0) out[0] = -(red[0] + red[1] + red[2] + red[3]) / (float)NN;
}

extern "C" void kernel_launch(void* const* d_in, const int* in_sizes, int n_in,
                              void* d_out, int out_size, void* d_ws, size_t ws_size,
                              hipStream_t stream) {
    const float* zi = (const float*)d_in[0];
    const float* zj = (const float*)d_in[1];

    __hip_bfloat16* M = (__hip_bfloat16*)d_ws;                       // 8 MB
    float* rowsum  = (float*)((char*)d_ws + (size_t)NN * DD * 2);    // 32 KB
    float* targets = rowsum + NN;                                    // 32 KB
    float* out = (float*)d_out;

    normalize_kernel<<<NN / 4, 256, 0, stream>>>(zi, zj, M, rowsum);
    gram_lse_kernel<<<NBLK, 256, 0, stream>>>(M, rowsum, targets);
    finalize_kernel<<<1, 256, 0, stream>>>(rowsum, targets, out);
}

// Round 5
// 100.718 us; speedup vs baseline: 1.7779x; 1.2258x over previous
//
#include <hip/hip_runtime.h>
#include <hip/hip_bf16.h>
#include <hip/hip_fp8.h>

// SimCLR NT-Xent loss on MI355X.
// loss = -(1/2B) sum_t [ 10*G[t,j0(t)] - (10 + log sum_{j!=t} exp(10*G[t,j]-10)) ]
// where G = M M^T, M = l2norm rows of [z_i; z_j], j0 = (t%B==0) ? 1 : 0.
// Round 5: fp8 e4m3 everywhere. Halves staged bytes AND doubles K-chunk to
// 128 at the same 32 KB LDS (16->8 barrier drains). XCD-banded tile order
// (M = 4 MB fp8 == one XCD L2). Relaxed atomics only (round-2 lesson).

#define BB 4096      // batch B
#define DD 512       // feature dim (bytes per row in fp8)
#define NN 8192      // 2B rows of G
#define TILE 128     // block tile (rows x cols)
#define KB 128       // K bytes (=elements) staged per LDS chunk
#define NBLK 2080    // 64*65/2 upper-triangle block tiles

typedef __attribute__((ext_vector_type(4))) float f32x4;

#define AS1 __attribute__((address_space(1)))
#define AS3 __attribute__((address_space(3)))
static __device__ __forceinline__ void gload_lds16(const void* g, void* l) {
    __builtin_amdgcn_global_load_lds((const AS1 void*)g, (AS3 void*)l, 16, 0, 0);
}

// ---------------- kernel 1: L2-normalize rows, cast to fp8; zero rowsum ----
// One wave per row: 64 lanes x 8 f32, shuffle reduce, no LDS/barrier.
__global__ __launch_bounds__(256)
void normalize_kernel(const float* __restrict__ zi, const float* __restrict__ zj,
                      unsigned char* __restrict__ M, float* __restrict__ rowsum) {
    const int wave = threadIdx.x >> 6;
    const int lane = threadIdx.x & 63;
    const int row  = blockIdx.x * 4 + wave;      // 2048 blocks * 4 rows
    if (threadIdx.x < 4) rowsum[blockIdx.x * 4 + threadIdx.x] = 0.f;
    const float* src = (row < BB) ? (zi + (size_t)row * DD)
                                  : (zj + (size_t)(row - BB) * DD);
    float4 v0 = ((const float4*)src)[lane * 2 + 0];
    float4 v1 = ((const float4*)src)[lane * 2 + 1];
    float ss = v0.x*v0.x + v0.y*v0.y + v0.z*v0.z + v0.w*v0.w
             + v1.x*v1.x + v1.y*v1.y + v1.z*v1.z + v1.w*v1.w;
    #pragma unroll
    for (int off = 1; off <= 32; off <<= 1) ss += __shfl_xor(ss, off);
    const float inv = rsqrtf(ss);
    const float vals[8] = {v0.x*inv, v0.y*inv, v0.z*inv, v0.w*inv,
                           v1.x*inv, v1.y*inv, v1.z*inv, v1.w*inv};
    union { long u; unsigned char b[8]; } pk;
    #pragma unroll
    for (int j = 0; j < 8; ++j)
        pk.b[j] = __hip_cvt_float_to_fp8(vals[j], __HIP_SATFINITE, __HIP_E4M3);
    ((long*)(M + (size_t)row * DD))[lane] = pk.u;
}

// ---------------- kernel 2: Gram tile + exp row/col sums -------------------
// 2080 blocks, one upper-triangle 128x128 tile each (by >= bx).
// Wave w: rows wr=(w>>1)*64, cols wc=(w&1)*64 within the tile.
// LDS: row-major 128 rows x 128 B, XOR-swizzled 16B granules
//   granule q holds (row=q>>3, g=(q&7)^((q>>3)&7)); gather side inverts the
//   swizzle so global_load_lds's lane-linear dest constraint is satisfied.
__global__ __launch_bounds__(256, 4)
void gram_lse_kernel(const unsigned char* __restrict__ Mg,
                     float* __restrict__ rowsum, float* __restrict__ targets) {
    __shared__ __align__(16) char As[TILE * KB];   // 16 KB
    __shared__ __align__(16) char Bs[TILE * KB];   // 16 KB

    // XCD-banded order: dispatch d -> band d%8 (one XCD), 260 tiles per band.
    const int d = blockIdx.x;
    const int p = (d & 7) * 260 + (d >> 3);
    // triangular decode: p -> (bx, by) with by >= bx
    int by = (int)((sqrtf(8.0f * (float)p + 1.0f) - 1.0f) * 0.5f);
    while ((by + 1) * (by + 2) / 2 <= p) ++by;
    while (by * (by + 1) / 2 > p) --by;
    const int bx = p - by * (by + 1) / 2;

    const int rowBase = bx * TILE;
    const int colBase = by * TILE;
    const bool diag = (bx == by);
    const int tid  = threadIdx.x;
    const int wave = tid >> 6;
    const int lane = tid & 63;
    const int wr = (wave >> 1) * 64;
    const int wc = (wave & 1) * 64;
    const int l15 = lane & 15;
    const int l4  = lane >> 4;          // quad 0..3

    // staging gather pattern (constant per thread across issues & k0):
    const int sg  = (tid & 7) ^ ((tid >> 3) & 7);   // source granule within row
    const int sr0 = tid >> 3;                        // source row base (+32/issue)
    const unsigned char* gA0 = Mg + (size_t)(rowBase + sr0) * DD + sg * 16;
    const unsigned char* gB0 = Mg + (size_t)(colBase + sr0) * DD + sg * 16;
    char* lA0 = As + tid * 16;                       // granule q = tid (+256/issue)
    char* lB0 = Bs + tid * 16;

    // fragment read pattern: row r fragment for k-step ks at
    //   r*128 + (((ks*2 + (l4>>1)) ^ (r&7))*16) + (l4&1)*8   [8B aligned]
    // r&7 == l15&7 for all mi/ni since tile row strides are multiples of 16.
    const int r7 = l15 & 7;
    const int qh = l4 >> 1, ql = l4 & 1;
    const int aoff0 = (wr + l15) * KB + ql * 8;
    const int boff0 = (wc + l15) * KB + ql * 8;
    const char* BsP = diag ? As : Bs;

    f32x4 acc[4][4] = {};

    for (int k0 = 0; k0 < DD; k0 += KB) {
        __syncthreads();   // previous-iteration LDS reads done
        #pragma unroll
        for (int i = 0; i < 4; ++i)
            gload_lds16(gA0 + k0 + (size_t)i * 32 * DD, lA0 + i * 4096);
        if (!diag) {
            #pragma unroll
            for (int i = 0; i < 4; ++i)
                gload_lds16(gB0 + k0 + (size_t)i * 32 * DD, lB0 + i * 4096);
        }
        __syncthreads();   // drains vmcnt(0): staging complete
        #pragma unroll
        for (int ks = 0; ks < 4; ++ks) {
            const int so = ((((ks << 1) | qh) ^ r7) << 4);
            long a[4], b[4];
            #pragma unroll
            for (int mi = 0; mi < 4; ++mi)
                a[mi] = *(const long*)(As + aoff0 + mi * 2048 + so);
            #pragma unroll
            for (int ni = 0; ni < 4; ++ni)
                b[ni] = *(const long*)(BsP + boff0 + ni * 2048 + so);
            #pragma unroll
            for (int mi = 0; mi < 4; ++mi)
                #pragma unroll
                for (int ni = 0; ni < 4; ++ni)
                    acc[mi][ni] = __builtin_amdgcn_mfma_f32_16x16x32_fp8_fp8(
                        a[mi], b[ni], acc[mi][ni], 0, 0, 0);
        }
    }

    // ---- epilogue ----
    // C/D layout: col = lane&15, row = (lane>>4)*4 + reg  (dtype-independent)
    float cs[4] = {0.f, 0.f, 0.f, 0.f};   // column partials (off-diag tiles)
    #pragma unroll
    for (int mi = 0; mi < 4; ++mi) {
        float rs[4] = {0.f, 0.f, 0.f, 0.f};
        #pragma unroll
        for (int ni = 0; ni < 4; ++ni) {
            const int gcol = colBase + wc + ni * 16 + l15;
            #pragma unroll
            for (int r = 0; r < 4; ++r) {
                const int grow = rowBase + wr + mi * 16 + l4 * 4 + r;
                float logit = 10.f * acc[mi][ni][r];
                float e = __expf(logit - 10.f);
                if (grow == gcol) e = 0.f;     // exclude diagonal exactly
                rs[r] += e;
                cs[ni] += e;
                // targets: rows 0/1 of G give 10*G[t, j0] transposed.
                // Only bx==0 blocks write; disjoint col ranges -> plain store.
                if (rowBase == 0 && grow < 2) {
                    const int j0 = ((gcol & (BB - 1)) == 0) ? 1 : 0;
                    if (grow == j0) targets[gcol] = logit;
                }
            }
        }
        #pragma unroll
        for (int m = 1; m <= 8; m <<= 1)
            #pragma unroll
            for (int r = 0; r < 4; ++r)
                rs[r] += __shfl_xor(rs[r], m);
        if (l15 == 0) {
            #pragma unroll
            for (int r = 0; r < 4; ++r)
                atomicAdd(&rowsum[rowBase + wr + mi * 16 + l4 * 4 + r], rs[r]);
        }
    }
    if (!diag) {
        #pragma unroll
        for (int ni = 0; ni < 4; ++ni) {
            cs[ni] += __shfl_xor(cs[ni], 16);
            cs[ni] += __shfl_xor(cs[ni], 32);
        }
        if (l4 == 0) {
            #pragma unroll
            for (int ni = 0; ni < 4; ++ni)
                atomicAdd(&rowsum[colBase + wc + ni * 16 + l15], cs[ni]);
        }
    }
}

// ---------------- kernel 3: final scalar reduction -------------------------
__global__ __launch_bounds__(1024)
void finalize_kernel(const float* __restrict__ rowsum,
                     const float* __restrict__ targets, float* __restrict__ out) {
    const int tid = threadIdx.x;
    float s = 0.f;
    #pragma unroll
    for (int t = tid; t < NN; t += 1024)
        s += targets[t] - 10.f - __logf(rowsum[t]);
    #pragma unroll
    for (int off = 1; off <= 32; off <<= 1) s += __shfl_xor(s, off);
    __shared__ float red[16];
    if ((tid & 63) == 0) red[tid >> 6] = s;
    __syncthreads();
    if (tid == 0) {
        float t = 0.f;
        #pragma unroll
        for (int i = 0; i < 16; ++i) t += red[i];
        out[0] = -t / (float)NN;
    }
}

extern "C" void kernel_launch(void* const* d_in, const int* in_sizes, int n_in,
                              void* d_out, int out_size, void* d_ws, size_t ws_size,
                              hipStream_t stream) {
    const float* zi = (const float*)d_in[0];
    const float* zj = (const float*)d_in[1];

    unsigned char* M = (unsigned char*)d_ws;                         // 4 MB fp8
    float* rowsum  = (float*)((char*)d_ws + (size_t)NN * DD);        // 32 KB
    float* targets = rowsum + NN;                                    // 32 KB
    float* out = (float*)d_out;

    normalize_kernel<<<NN / 4, 256, 0, stream>>>(zi, zj, M, rowsum);
    gram_lse_kernel<<<NBLK, 256, 0, stream>>>(M, rowsum, targets);
    finalize_kernel<<<1, 1024, 0, stream>>>(rowsum, targets, out);
}